// Round 9
// baseline (212.237 us; speedup 1.0000x reference)
//
#include <hip/hip_runtime.h>

typedef __attribute__((ext_vector_type(8))) short short8;
typedef __attribute__((ext_vector_type(4))) short sh4;
typedef __attribute__((ext_vector_type(4))) float f32x4;

#define BH 2097152   // B*H = 4096*512
#define NK 32

// f32 -> bf16 round-to-nearest-even
static __device__ __forceinline__ short f2bf(float f) {
  union { float f; unsigned int u; } c; c.f = f;
  unsigned int u = c.u + 0x7FFFu + ((c.u >> 16) & 1u);
  return (short)(u >> 16);
}
static __device__ __forceinline__ float bf2f(short s) {
  union { unsigned int u; float f; } c;
  c.u = ((unsigned int)(unsigned short)s) << 16;
  return c.f;
}
static __device__ __forceinline__ f32x4 ntload(const float* p) {
  return __builtin_nontemporal_load((const f32x4*)p);
}
static __device__ __forceinline__ void ntstore(float* p, f32x4 v) {
  __builtin_nontemporal_store(v, (f32x4*)p);
}

// ---------------- ws layout (shorts) ----------------
#define WS_XH     0          // [4096][1024] bf16 concat(sample,hidden)
#define WS_MEMPB  4194304    // [4096][512]
#define WS_WI     6291456    // [512][1024]
#define WS_WO     6815744
#define WS_WC     7340032
#define WS_WM     7864320    // [512][1536]
#define WS_WOUT   8650752    // [512][512]
#define WS_HIDB   8912896    // [4096][512] bf16 hidden_new
#define WS_IGB    11010048   // [4096][512] bf16 gates
#define WS_OGB    13107200
#define WS_CGB    15204352
#define WS_END    17301504
#define FAST_NEED_BYTES ((size_t)WS_END * 2)

// ============================ FAST PATH ============================

__global__ __launch_bounds__(256) void prep(
    const float* __restrict__ sample, const float* __restrict__ hidden,
    const float* __restrict__ memp,
    const float* __restrict__ wi, const float* __restrict__ wo,
    const float* __restrict__ wc, const float* __restrict__ wm,
    const float* __restrict__ wout, short* __restrict__ ws) {
  const size_t v = ((size_t)blockIdx.x * 256 + threadIdx.x) * 4;
  const float* src;
  short* dst;
  if (v < 2097152) {                     // sample -> xh[:, :512]
    const size_t r = v >> 9, c = v & 511;
    src = sample + v; dst = ws + WS_XH + r * 1024 + c;
  } else if (v < 4194304) {              // hidden -> xh[:, 512:]
    const size_t u = v - 2097152, r = u >> 9, c = u & 511;
    src = hidden + u; dst = ws + WS_XH + r * 1024 + 512 + c;
  } else if (v < 6291456) {              // memp
    const size_t u = v - 4194304; src = memp + u; dst = ws + WS_MEMPB + u;
  } else if (v < 6815744) {
    const size_t u = v - 6291456; src = wi + u; dst = ws + WS_WI + u;
  } else if (v < 7340032) {
    const size_t u = v - 6815744; src = wo + u; dst = ws + WS_WO + u;
  } else if (v < 7864320) {
    const size_t u = v - 7340032; src = wc + u; dst = ws + WS_WC + u;
  } else if (v < 8650752) {
    const size_t u = v - 7864320; src = wm + u; dst = ws + WS_WM + u;
  } else {                               // wout, ends at 8912896
    const size_t u = v - 8650752; src = wout + u; dst = ws + WS_WOUT + u;
  }
  const f32x4 x = *(const f32x4*)src;
  sh4 s;
#pragma unroll
  for (int j = 0; j < 4; ++j) s[j] = f2bf(x[j]);
  *(sh4*)dst = s;
}

struct FastArgs {
  const short *xh, *mempb, *hidb;
  const short *W[5];
  const float *bia[5];
  short *gdst[3];     // igb, ogb, cgb (bf16)
  float *memo, *out0; // f32 outputs
};

// bf16 GEMM, 128x128 tile, BK=128 (halved barrier count vs BK=64 — occupancy
// is grid-limited to 2 blocks/CU here, so the 64 KB LDS costs nothing; m132's
// BK=128 regression was an occupancy loss we don't pay).
// mode0: y>>2 -> gate via gmap {m,i,o,c}; nsub=y&3.  mode1: gate4 out GEMM.
__global__ __launch_bounds__(256) void gemm_fast(FastArgs a, int mode) {
  __shared__ short lA[128 * 128];
  __shared__ short lB[128 * 128];
  const int t = threadIdx.x;
  const int lane = t & 63;
  const int wv = t >> 6;
  const int mt = blockIdx.x;
  int gate, nsub;
  if (mode == 0) {
    const int gmap[4] = {3, 0, 1, 2};   // m first (longest K)
    gate = gmap[blockIdx.y >> 2]; nsub = blockIdx.y & 3;
  } else { gate = 4; nsub = blockIdx.y; }
  const short* W = a.W[gate];
  const int Klen = (gate == 3) ? 1536 : (gate == 4 ? 512 : 1024);
  const int m0 = mt * 128;
  const int n0 = nsub * 128;

  f32x4 acc[4][4];
  const f32x4 z = {0.f, 0.f, 0.f, 0.f};
#pragma unroll
  for (int i = 0; i < 4; ++i)
#pragma unroll
    for (int j = 0; j < 4; ++j) acc[i][j] = z;

  const int wr = wv >> 1, wc2 = wv & 1;
  const int Ktiles = Klen >> 7;
  for (int kt = 0; kt < Ktiles; ++kt) {
    const int kb = kt << 7;
    // stage A tile [128 rows][128 k]: 8 passes x 256 threads x 16B
#pragma unroll
    for (int it = 0; it < 8; ++it) {
      const int chunk = it * 256 + t;
      const int row = chunk >> 4;          // 0..127
      const int kk = (chunk & 15) << 3;    // 0..120
      const int gk = kb + kk;
      const short* src;
      if (gate == 4)                    src = a.hidb  + (size_t)(m0 + row) * 512 + gk;
      else if (gate != 3 || gk < 1024)  src = a.xh    + (size_t)(m0 + row) * 1024 + gk;
      else                              src = a.mempb + (size_t)(m0 + row) * 512 + (gk - 1024);
      __builtin_amdgcn_global_load_lds(
          (const __attribute__((address_space(1))) void*)src,
          (__attribute__((address_space(3))) void*)(lA + (size_t)(it * 256 + wv * 64) * 8),
          16, 0, 0);
    }
    // stage W tile [128 n][128 k]
#pragma unroll
    for (int it = 0; it < 8; ++it) {
      const int chunk = it * 256 + t;
      const int row = chunk >> 4;
      const int kk = (chunk & 15) << 3;
      const short* src = W + (size_t)(n0 + row) * Klen + kb + kk;
      __builtin_amdgcn_global_load_lds(
          (const __attribute__((address_space(1))) void*)src,
          (__attribute__((address_space(3))) void*)(lB + (size_t)(it * 256 + wv * 64) * 8),
          16, 0, 0);
    }
    __syncthreads();
#pragma unroll
    for (int ks = 0; ks < 4; ++ks) {
      short8 av[4], bv[4];
#pragma unroll
      for (int mi = 0; mi < 4; ++mi)
        av[mi] = *(const short8*)(lA + (wr * 64 + mi * 16 + (lane & 15)) * 128 + ks * 32 + ((lane >> 4) << 3));
#pragma unroll
      for (int ni = 0; ni < 4; ++ni)
        bv[ni] = *(const short8*)(lB + (wc2 * 64 + ni * 16 + (lane & 15)) * 128 + ks * 32 + ((lane >> 4) << 3));
#pragma unroll
      for (int mi = 0; mi < 4; ++mi)
#pragma unroll
        for (int ni = 0; ni < 4; ++ni)
          acc[mi][ni] = __builtin_amdgcn_mfma_f32_16x16x32_bf16(av[mi], bv[ni], acc[mi][ni], 0, 0, 0);
    }
    __syncthreads();
  }

  // epilogue: C/D layout col = lane&15 (n), row = 4*(lane>>4)+r (m)
  const float* bias = a.bia[gate];
  const int rg = lane >> 4;
  const int ci = lane & 15;
#pragma unroll
  for (int mi = 0; mi < 4; ++mi) {
#pragma unroll
    for (int ni = 0; ni < 4; ++ni) {
      const int col = n0 + wc2 * 64 + ni * 16 + ci;
      const float bvl = bias[col];
#pragma unroll
      for (int r = 0; r < 4; ++r) {
        const int row = m0 + wr * 64 + mi * 16 + rg * 4 + r;
        const float v = acc[mi][ni][r] + bvl;
        const size_t o = (size_t)row * 512 + col;
        if (gate == 0)      a.gdst[0][o] = f2bf(1.f / (1.f + __expf(-v)));
        else if (gate == 1) a.gdst[1][o] = f2bf(1.f / (1.f + __expf(-v)));
        else if (gate == 2) a.gdst[2][o] = f2bf(1.f - 2.f / (1.f + __expf(2.f * v)));
        else if (gate == 3) a.memo[o] = 0.5f / (1.f + __expf(-v));
        else                a.out0[o] = v;
      }
    }
  }
}

// Fused cumprod filter + cell shift + cell_new + hidden_new (+ bf16 hidden copy).
// Nontemporal on the single-use streams; (256,8) -> 32 waves/CU.
__global__ __launch_bounds__(256, 8) void cell_update_b(
    const float* __restrict__ cell, const short* __restrict__ igb,
    const short* __restrict__ ogb, const short* __restrict__ cgb,
    const float* __restrict__ mem, float* __restrict__ upd,
    float* __restrict__ hid, short* __restrict__ hidb)
{
  const size_t idx = ((size_t)blockIdx.x * 256 + threadIdx.x) * 4;
  const f32x4 dv = *(const f32x4*)(mem + idx);
  const sh4 iv = *(const sh4*)(igb + idx);
  const sh4 ov = *(const sh4*)(ogb + idx);
  const sh4 gv = *(const sh4*)(cgb + idx);
  float p[4], acc[4];
#pragma unroll
  for (int j = 0; j < 4; ++j) { p[j] = 1.f; acc[j] = 0.f; }
#pragma unroll
  for (int i = 0; i < 32; ++i) {
    const int k = 31 - i;
    const f32x4 c = ntload(cell + (size_t)k * BH + idx);
    const float inv = 1.f / (float)(i + 1);
#pragma unroll
    for (int j = 0; j < 4; ++j) {
      p[j] *= ((float)i - dv[j]) * inv;    // cumprod factor (i - d)/(i+1)
      acc[j] += c[j] * p[j];
    }
    if (k >= 1) ntstore(upd + (size_t)(k - 1) * BH + idx, c);  // shift copy
  }
  f32x4 cno, ho; sh4 hb;
#pragma unroll
  for (int j = 0; j < 4; ++j) {
    const float cn = -acc[j] + bf2f(gv[j]) * bf2f(iv[j]);
    cno[j] = cn;
    const float th = 1.f - 2.f / (1.f + __expf(2.f * cn));  // tanh, overflow-safe
    const float h = bf2f(ov[j]) * th;
    ho[j] = h; hb[j] = f2bf(h);
  }
  ntstore(upd + (size_t)31 * BH + idx, cno);
  *(f32x4*)(hid + idx) = ho;
  *(sh4*)(hidb + idx) = hb;
}

// ============================ FALLBACK (round-3, passed) ============================

struct GemmArgs {
  const float *sample, *hidden, *memp, *hid_in;
  const float *W[5];
  const float *bia[5];
  float *dst[5];
};

__global__ __launch_bounds__(256) void gemm_all(GemmArgs g, int mode) {
  __shared__ short lA[128 * 64];
  __shared__ short lB[128 * 64];
  const int t = threadIdx.x;
  const int lane = t & 63;
  const int mt = blockIdx.x;
  int gate, nsub;
  if (mode == 0) { gate = blockIdx.y >> 2; nsub = blockIdx.y & 3; }
  else           { gate = 4;               nsub = blockIdx.y; }
  const float* W = g.W[gate];
  const float* bias = g.bia[gate];
  float* dst = g.dst[gate];
  const int Klen = (gate == 3) ? 1536 : (gate == 4 ? 512 : 1024);
  const int m0 = mt * 128;
  const int n0 = nsub * 128;

  f32x4 acc[4][4];
  const f32x4 z = {0.f, 0.f, 0.f, 0.f};
#pragma unroll
  for (int i = 0; i < 4; ++i)
#pragma unroll
    for (int j = 0; j < 4; ++j) acc[i][j] = z;

  const int wv = t >> 6;
  const int wr = wv >> 1, wc = wv & 1;
  const int Ktiles = Klen >> 6;
  for (int kt = 0; kt < Ktiles; ++kt) {
    const int kb = kt << 6;
#pragma unroll
    for (int it = 0; it < 4; ++it) {
      const int chunk = it * 256 + t;
      const int row = chunk >> 3;
      const int kk = (chunk & 7) << 3;
      const int gk = kb + kk;
      const float* src;
      if (mode == 1)      src = g.hid_in + (size_t)(m0 + row) * 512 + gk;
      else if (gk < 512)  src = g.sample + (size_t)(m0 + row) * 512 + gk;
      else if (gk < 1024) src = g.hidden + (size_t)(m0 + row) * 512 + (gk - 512);
      else                src = g.memp   + (size_t)(m0 + row) * 512 + (gk - 1024);
      const f32x4 v0 = *(const f32x4*)src;
      const f32x4 v1 = *(const f32x4*)(src + 4);
      short8 s;
#pragma unroll
      for (int j = 0; j < 4; ++j) { s[j] = f2bf(v0[j]); s[4 + j] = f2bf(v1[j]); }
      *(short8*)(lA + row * 64 + kk) = s;
    }
#pragma unroll
    for (int it = 0; it < 4; ++it) {
      const int chunk = it * 256 + t;
      const int row = chunk >> 3;
      const int kk = (chunk & 7) << 3;
      const float* src = W + (size_t)(n0 + row) * Klen + kb + kk;
      const f32x4 v0 = *(const f32x4*)src;
      const f32x4 v1 = *(const f32x4*)(src + 4);
      short8 s;
#pragma unroll
      for (int j = 0; j < 4; ++j) { s[j] = f2bf(v0[j]); s[4 + j] = f2bf(v1[j]); }
      *(short8*)(lB + row * 64 + kk) = s;
    }
    __syncthreads();
#pragma unroll
    for (int ks = 0; ks < 2; ++ks) {
      short8 av[4], bv[4];
#pragma unroll
      for (int mi = 0; mi < 4; ++mi)
        av[mi] = *(const short8*)(lA + (wr * 64 + mi * 16 + (lane & 15)) * 64 + ks * 32 + ((lane >> 4) << 3));
#pragma unroll
      for (int ni = 0; ni < 4; ++ni)
        bv[ni] = *(const short8*)(lB + (wc * 64 + ni * 16 + (lane & 15)) * 64 + ks * 32 + ((lane >> 4) << 3));
#pragma unroll
      for (int mi = 0; mi < 4; ++mi)
#pragma unroll
        for (int ni = 0; ni < 4; ++ni)
          acc[mi][ni] = __builtin_amdgcn_mfma_f32_16x16x32_bf16(av[mi], bv[ni], acc[mi][ni], 0, 0, 0);
    }
    __syncthreads();
  }

  const int rg = lane >> 4;
  const int ci = lane & 15;
#pragma unroll
  for (int mi = 0; mi < 4; ++mi) {
#pragma unroll
    for (int ni = 0; ni < 4; ++ni) {
      const int col = n0 + wc * 64 + ni * 16 + ci;
      const float bvl = bias[col];
#pragma unroll
      for (int r = 0; r < 4; ++r) {
        const int row = m0 + wr * 64 + mi * 16 + rg * 4 + r;
        const float v = acc[mi][ni][r] + bvl;
        float o;
        if (gate == 0 || gate == 1)  o = 1.f / (1.f + __expf(-v));
        else if (gate == 2)          o = 1.f - 2.f / (1.f + __expf(2.f * v));
        else if (gate == 3)          o = 0.5f / (1.f + __expf(-v));
        else                         o = v;
        dst[(size_t)row * 512 + col] = o;
      }
    }
  }
}

__global__ __launch_bounds__(256) void cell_update(
    const float* __restrict__ cell, const float* ig, const float* og, const float* cg,
    const float* mem, float* upd, float* __restrict__ hid)
{
  const size_t idx = ((size_t)blockIdx.x * 256 + threadIdx.x) * 4;
  const f32x4 dv = *(const f32x4*)(mem + idx);
  const f32x4 iv = *(const f32x4*)(ig + idx);
  const f32x4 ov = *(const f32x4*)(og + idx);
  const f32x4 gv = *(const f32x4*)(cg + idx);
  asm volatile("" ::: "memory");
  float p[4], acc[4];
#pragma unroll
  for (int j = 0; j < 4; ++j) { p[j] = 1.f; acc[j] = 0.f; }
#pragma unroll
  for (int i = 0; i < 32; ++i) {
    const int k = 31 - i;
    const f32x4 c = *(const f32x4*)(cell + (size_t)k * BH + idx);
    const float inv = 1.f / (float)(i + 1);
#pragma unroll
    for (int j = 0; j < 4; ++j) {
      p[j] *= ((float)i - dv[j]) * inv;
      acc[j] += c[j] * p[j];
    }
    if (k >= 1) *(f32x4*)(upd + (size_t)(k - 1) * BH + idx) = c;
  }
  f32x4 cno, ho;
#pragma unroll
  for (int j = 0; j < 4; ++j) {
    const float cn = -acc[j] + gv[j] * iv[j];
    cno[j] = cn;
    const float th = 1.f - 2.f / (1.f + __expf(2.f * cn));
    ho[j] = ov[j] * th;
  }
  *(f32x4*)(upd + (size_t)31 * BH + idx) = cno;
  *(f32x4*)(hid + idx) = ho;
}

// ============================ launch ============================

extern "C" void kernel_launch(void* const* d_in, const int* in_sizes, int n_in,
                              void* d_out, int out_size, void* d_ws, size_t ws_size,
                              hipStream_t stream) {
  const float* sample = (const float*)d_in[0];
  const float* hidden = (const float*)d_in[1];
  const float* cell   = (const float*)d_in[2];
  const float* memp   = (const float*)d_in[3];

  float* out0 = (float*)d_out;                 // [B,O]   output
  float* hid  = out0 + (size_t)BH;             // [B,H]   hidden_new
  float* upd  = hid + (size_t)BH;              // [K,B,H] updated_cell_states
  float* memo = upd + (size_t)NK * BH;         // [B,H]   mem_new

  if (ws_size >= FAST_NEED_BYTES) {
    short* ws = (short*)d_ws;
    hipLaunchKernelGGL(prep, dim3(8704), dim3(256), 0, stream,
                       sample, hidden, memp,
                       (const float*)d_in[4], (const float*)d_in[6],
                       (const float*)d_in[10], (const float*)d_in[8],
                       (const float*)d_in[12], ws);
    FastArgs a;
    a.xh = ws + WS_XH; a.mempb = ws + WS_MEMPB; a.hidb = ws + WS_HIDB;
    a.W[0] = ws + WS_WI; a.W[1] = ws + WS_WO; a.W[2] = ws + WS_WC;
    a.W[3] = ws + WS_WM; a.W[4] = ws + WS_WOUT;
    a.bia[0] = (const float*)d_in[5];  a.bia[1] = (const float*)d_in[7];
    a.bia[2] = (const float*)d_in[11]; a.bia[3] = (const float*)d_in[9];
    a.bia[4] = (const float*)d_in[13];
    a.gdst[0] = ws + WS_IGB; a.gdst[1] = ws + WS_OGB; a.gdst[2] = ws + WS_CGB;
    a.memo = memo; a.out0 = out0;

    hipLaunchKernelGGL(gemm_fast, dim3(32, 16), dim3(256), 0, stream, a, 0);
    hipLaunchKernelGGL(cell_update_b, dim3(2048), dim3(256), 0, stream,
                       cell, (const short*)a.gdst[0], (const short*)a.gdst[1],
                       (const short*)a.gdst[2], (const float*)memo, upd, hid,
                       ws + WS_HIDB);
    hipLaunchKernelGGL(gemm_fast, dim3(32, 4), dim3(256), 0, stream, a, 1);
    return;
  }

  // fallback: round-3 path (passed)
  float* ig;
  float* og;
  float* cg;
  if (ws_size >= (size_t)3 * BH * sizeof(float)) {
    ig = (float*)d_ws; og = ig + (size_t)BH; cg = og + (size_t)BH;
  } else {
    ig = upd; og = upd + (size_t)BH; cg = upd + 2 * (size_t)BH;
  }
  GemmArgs g;
  g.sample = sample; g.hidden = hidden; g.memp = memp; g.hid_in = hid;
  g.W[0] = (const float*)d_in[4];  g.bia[0] = (const float*)d_in[5];
  g.W[1] = (const float*)d_in[6];  g.bia[1] = (const float*)d_in[7];
  g.W[3] = (const float*)d_in[8];  g.bia[3] = (const float*)d_in[9];
  g.W[2] = (const float*)d_in[10]; g.bia[2] = (const float*)d_in[11];
  g.W[4] = (const float*)d_in[12]; g.bia[4] = (const float*)d_in[13];
  g.dst[0] = ig; g.dst[1] = og; g.dst[2] = cg; g.dst[3] = memo; g.dst[4] = out0;

  hipLaunchKernelGGL(gemm_all, dim3(32, 16), dim3(256), 0, stream, g, 0);
  hipLaunchKernelGGL(cell_update, dim3(2048), dim3(256), 0, stream,
                     cell, (const float*)ig, (const float*)og, (const float*)cg,
                     (const float*)memo, upd, hid);
  hipLaunchKernelGGL(gemm_all, dim3(32, 4), dim3(256), 0, stream, g, 1);
}

// Round 10
// 187.277 us; speedup vs baseline: 1.1333x; 1.1333x over previous
//
#include <hip/hip_runtime.h>

typedef __attribute__((ext_vector_type(8))) short short8;
typedef __attribute__((ext_vector_type(4))) short sh4;
typedef __attribute__((ext_vector_type(4))) float f32x4;

#define BH 2097152   // B*H = 4096*512
#define NK 32

// f32 -> bf16 round-to-nearest-even
static __device__ __forceinline__ short f2bf(float f) {
  union { float f; unsigned int u; } c; c.f = f;
  unsigned int u = c.u + 0x7FFFu + ((c.u >> 16) & 1u);
  return (short)(u >> 16);
}
static __device__ __forceinline__ float bf2f(short s) {
  union { unsigned int u; float f; } c;
  c.u = ((unsigned int)(unsigned short)s) << 16;
  return c.f;
}
static __device__ __forceinline__ f32x4 ntload(const float* p) {
  return __builtin_nontemporal_load((const f32x4*)p);
}
static __device__ __forceinline__ void ntstore(float* p, f32x4 v) {
  __builtin_nontemporal_store(v, (f32x4*)p);
}

// ---------------- ws layout (shorts) ----------------
#define WS_XH     0          // [4096][1024] bf16 concat(sample,hidden)
#define WS_MEMPB  4194304    // [4096][512]
#define WS_WI     6291456    // [512][1024]
#define WS_WO     6815744
#define WS_WC     7340032
#define WS_WM     7864320    // [512][1536]
#define WS_WOUT   8650752    // [512][512]
#define WS_HIDB   8912896    // [4096][512] bf16 hidden_new
#define WS_IGB    11010048   // [4096][512] bf16 gates
#define WS_OGB    13107200
#define WS_CGB    15204352
#define WS_END    17301504
#define FAST_NEED_BYTES ((size_t)WS_END * 2)

// ============================ FAST PATH ============================

__global__ __launch_bounds__(256) void prep(
    const float* __restrict__ sample, const float* __restrict__ hidden,
    const float* __restrict__ memp,
    const float* __restrict__ wi, const float* __restrict__ wo,
    const float* __restrict__ wc, const float* __restrict__ wm,
    const float* __restrict__ wout, short* __restrict__ ws) {
  const size_t v = ((size_t)blockIdx.x * 256 + threadIdx.x) * 4;
  const float* src;
  short* dst;
  if (v < 2097152) {                     // sample -> xh[:, :512]
    const size_t r = v >> 9, c = v & 511;
    src = sample + v; dst = ws + WS_XH + r * 1024 + c;
  } else if (v < 4194304) {              // hidden -> xh[:, 512:]
    const size_t u = v - 2097152, r = u >> 9, c = u & 511;
    src = hidden + u; dst = ws + WS_XH + r * 1024 + 512 + c;
  } else if (v < 6291456) {              // memp
    const size_t u = v - 4194304; src = memp + u; dst = ws + WS_MEMPB + u;
  } else if (v < 6815744) {
    const size_t u = v - 6291456; src = wi + u; dst = ws + WS_WI + u;
  } else if (v < 7340032) {
    const size_t u = v - 6815744; src = wo + u; dst = ws + WS_WO + u;
  } else if (v < 7864320) {
    const size_t u = v - 7340032; src = wc + u; dst = ws + WS_WC + u;
  } else if (v < 8650752) {
    const size_t u = v - 7864320; src = wm + u; dst = ws + WS_WM + u;
  } else {                               // wout, ends at 8912896
    const size_t u = v - 8650752; src = wout + u; dst = ws + WS_WOUT + u;
  }
  const f32x4 x = *(const f32x4*)src;
  sh4 s;
#pragma unroll
  for (int j = 0; j < 4; ++j) s[j] = f2bf(x[j]);
  *(sh4*)dst = s;
}

struct FastArgs {
  const short *xh, *mempb, *hidb;
  const short *W[5];
  const float *bia[5];
  short *gdst[3];     // igb, ogb, cgb (bf16)
  float *memo, *out0; // f32 outputs
};

// bf16 GEMM, 64x128 tile (M x N), BK=64. Doubles grid to 1024 blocks
// -> 4 blocks/CU co-resident (vs 2 at 128x128): inter-block overlap hides
// the per-block stage+vmcnt+barrier drain (m102 lever: 320->833 TF is
// 1->3 blocks/CU). LDS 24KB, ~110 VGPR.
// mode0: gate via gmap {m,i,o,c} of y>>2; nsub=y&3.  mode1: gate4 out GEMM.
__global__ __launch_bounds__(256) void gemm_fast(FastArgs a, int mode) {
  __shared__ short lA[64 * 64];
  __shared__ short lB[128 * 64];
  const int t = threadIdx.x;
  const int lane = t & 63;
  const int wv = t >> 6;
  const int mt = blockIdx.x;
  int gate, nsub;
  if (mode == 0) {
    const int gmap[4] = {3, 0, 1, 2};   // m first (longest K)
    gate = gmap[blockIdx.y >> 2]; nsub = blockIdx.y & 3;
  } else { gate = 4; nsub = blockIdx.y; }
  const short* W = a.W[gate];
  const int Klen = (gate == 3) ? 1536 : (gate == 4 ? 512 : 1024);
  const int m0 = mt * 64;
  const int n0 = nsub * 128;

  f32x4 acc[2][4];
  const f32x4 z = {0.f, 0.f, 0.f, 0.f};
#pragma unroll
  for (int i = 0; i < 2; ++i)
#pragma unroll
    for (int j = 0; j < 4; ++j) acc[i][j] = z;

  const int wr = wv >> 1, wc2 = wv & 1;   // wave sub-tile: 32 rows x 64 cols
  const int Ktiles = Klen >> 6;
  for (int kt = 0; kt < Ktiles; ++kt) {
    const int kb = kt << 6;
    // stage A tile [64 rows][64 k]: 2 passes x 256 threads x 16B (dest = 8*chunk shorts, linear)
#pragma unroll
    for (int it = 0; it < 2; ++it) {
      const int chunk = it * 256 + t;
      const int row = chunk >> 3;          // 0..63
      const int kk = (chunk & 7) << 3;     // 0..56
      const int gk = kb + kk;
      const short* src;
      if (gate == 4)                    src = a.hidb  + (size_t)(m0 + row) * 512 + gk;
      else if (gate != 3 || gk < 1024)  src = a.xh    + (size_t)(m0 + row) * 1024 + gk;
      else                              src = a.mempb + (size_t)(m0 + row) * 512 + (gk - 1024);
      __builtin_amdgcn_global_load_lds(
          (const __attribute__((address_space(1))) void*)src,
          (__attribute__((address_space(3))) void*)(lA + (size_t)(it * 256 + wv * 64) * 8),
          16, 0, 0);
    }
    // stage W tile [128 n][64 k]: 4 passes
#pragma unroll
    for (int it = 0; it < 4; ++it) {
      const int chunk = it * 256 + t;
      const int row = chunk >> 3;
      const int kk = (chunk & 7) << 3;
      const short* src = W + (size_t)(n0 + row) * Klen + kb + kk;
      __builtin_amdgcn_global_load_lds(
          (const __attribute__((address_space(1))) void*)src,
          (__attribute__((address_space(3))) void*)(lB + (size_t)(it * 256 + wv * 64) * 8),
          16, 0, 0);
    }
    __syncthreads();
#pragma unroll
    for (int ks = 0; ks < 2; ++ks) {
      short8 av[2], bv[4];
#pragma unroll
      for (int mi = 0; mi < 2; ++mi)
        av[mi] = *(const short8*)(lA + (wr * 32 + mi * 16 + (lane & 15)) * 64 + ks * 32 + ((lane >> 4) << 3));
#pragma unroll
      for (int ni = 0; ni < 4; ++ni)
        bv[ni] = *(const short8*)(lB + (wc2 * 64 + ni * 16 + (lane & 15)) * 64 + ks * 32 + ((lane >> 4) << 3));
#pragma unroll
      for (int mi = 0; mi < 2; ++mi)
#pragma unroll
        for (int ni = 0; ni < 4; ++ni)
          acc[mi][ni] = __builtin_amdgcn_mfma_f32_16x16x32_bf16(av[mi], bv[ni], acc[mi][ni], 0, 0, 0);
    }
    __syncthreads();
  }

  // epilogue: C/D layout col = lane&15 (n), row = 4*(lane>>4)+r (m)
  const float* bias = a.bia[gate];
  const int rg = lane >> 4;
  const int ci = lane & 15;
#pragma unroll
  for (int mi = 0; mi < 2; ++mi) {
#pragma unroll
    for (int ni = 0; ni < 4; ++ni) {
      const int col = n0 + wc2 * 64 + ni * 16 + ci;
      const float bvl = bias[col];
#pragma unroll
      for (int r = 0; r < 4; ++r) {
        const int row = m0 + wr * 32 + mi * 16 + rg * 4 + r;
        const float v = acc[mi][ni][r] + bvl;
        const size_t o = (size_t)row * 512 + col;
        if (gate == 0)      a.gdst[0][o] = f2bf(1.f / (1.f + __expf(-v)));
        else if (gate == 1) a.gdst[1][o] = f2bf(1.f / (1.f + __expf(-v)));
        else if (gate == 2) a.gdst[2][o] = f2bf(1.f - 2.f / (1.f + __expf(2.f * v)));
        else if (gate == 3) a.memo[o] = 0.5f / (1.f + __expf(-v));
        else                a.out0[o] = v;
      }
    }
  }
}

// Fused cumprod filter + cell shift + cell_new + hidden_new (+ bf16 hidden copy).
// Nontemporal on the single-use streams; (256,8) -> 32 waves/CU.
__global__ __launch_bounds__(256, 8) void cell_update_b(
    const float* __restrict__ cell, const short* __restrict__ igb,
    const short* __restrict__ ogb, const short* __restrict__ cgb,
    const float* __restrict__ mem, float* __restrict__ upd,
    float* __restrict__ hid, short* __restrict__ hidb)
{
  const size_t idx = ((size_t)blockIdx.x * 256 + threadIdx.x) * 4;
  const f32x4 dv = *(const f32x4*)(mem + idx);
  const sh4 iv = *(const sh4*)(igb + idx);
  const sh4 ov = *(const sh4*)(ogb + idx);
  const sh4 gv = *(const sh4*)(cgb + idx);
  float p[4], acc[4];
#pragma unroll
  for (int j = 0; j < 4; ++j) { p[j] = 1.f; acc[j] = 0.f; }
#pragma unroll
  for (int i = 0; i < 32; ++i) {
    const int k = 31 - i;
    const f32x4 c = ntload(cell + (size_t)k * BH + idx);
    const float inv = 1.f / (float)(i + 1);
#pragma unroll
    for (int j = 0; j < 4; ++j) {
      p[j] *= ((float)i - dv[j]) * inv;    // cumprod factor (i - d)/(i+1)
      acc[j] += c[j] * p[j];
    }
    if (k >= 1) ntstore(upd + (size_t)(k - 1) * BH + idx, c);  // shift copy
  }
  f32x4 cno, ho; sh4 hb;
#pragma unroll
  for (int j = 0; j < 4; ++j) {
    const float cn = -acc[j] + bf2f(gv[j]) * bf2f(iv[j]);
    cno[j] = cn;
    const float th = 1.f - 2.f / (1.f + __expf(2.f * cn));  // tanh, overflow-safe
    const float h = bf2f(ov[j]) * th;
    ho[j] = h; hb[j] = f2bf(h);
  }
  ntstore(upd + (size_t)31 * BH + idx, cno);
  *(f32x4*)(hid + idx) = ho;
  *(sh4*)(hidb + idx) = hb;
}

// ============================ FALLBACK (round-3, passed) ============================

struct GemmArgs {
  const float *sample, *hidden, *memp, *hid_in;
  const float *W[5];
  const float *bia[5];
  float *dst[5];
};

__global__ __launch_bounds__(256) void gemm_all(GemmArgs g, int mode) {
  __shared__ short lA[128 * 64];
  __shared__ short lB[128 * 64];
  const int t = threadIdx.x;
  const int lane = t & 63;
  const int mt = blockIdx.x;
  int gate, nsub;
  if (mode == 0) { gate = blockIdx.y >> 2; nsub = blockIdx.y & 3; }
  else           { gate = 4;               nsub = blockIdx.y; }
  const float* W = g.W[gate];
  const float* bias = g.bia[gate];
  float* dst = g.dst[gate];
  const int Klen = (gate == 3) ? 1536 : (gate == 4 ? 512 : 1024);
  const int m0 = mt * 128;
  const int n0 = nsub * 128;

  f32x4 acc[4][4];
  const f32x4 z = {0.f, 0.f, 0.f, 0.f};
#pragma unroll
  for (int i = 0; i < 4; ++i)
#pragma unroll
    for (int j = 0; j < 4; ++j) acc[i][j] = z;

  const int wv = t >> 6;
  const int wr = wv >> 1, wc = wv & 1;
  const int Ktiles = Klen >> 6;
  for (int kt = 0; kt < Ktiles; ++kt) {
    const int kb = kt << 6;
#pragma unroll
    for (int it = 0; it < 4; ++it) {
      const int chunk = it * 256 + t;
      const int row = chunk >> 3;
      const int kk = (chunk & 7) << 3;
      const int gk = kb + kk;
      const float* src;
      if (mode == 1)      src = g.hid_in + (size_t)(m0 + row) * 512 + gk;
      else if (gk < 512)  src = g.sample + (size_t)(m0 + row) * 512 + gk;
      else if (gk < 1024) src = g.hidden + (size_t)(m0 + row) * 512 + (gk - 512);
      else                src = g.memp   + (size_t)(m0 + row) * 512 + (gk - 1024);
      const f32x4 v0 = *(const f32x4*)src;
      const f32x4 v1 = *(const f32x4*)(src + 4);
      short8 s;
#pragma unroll
      for (int j = 0; j < 4; ++j) { s[j] = f2bf(v0[j]); s[4 + j] = f2bf(v1[j]); }
      *(short8*)(lA + row * 64 + kk) = s;
    }
#pragma unroll
    for (int it = 0; it < 4; ++it) {
      const int chunk = it * 256 + t;
      const int row = chunk >> 3;
      const int kk = (chunk & 7) << 3;
      const float* src = W + (size_t)(n0 + row) * Klen + kb + kk;
      const f32x4 v0 = *(const f32x4*)src;
      const f32x4 v1 = *(const f32x4*)(src + 4);
      short8 s;
#pragma unroll
      for (int j = 0; j < 4; ++j) { s[j] = f2bf(v0[j]); s[4 + j] = f2bf(v1[j]); }
      *(short8*)(lB + row * 64 + kk) = s;
    }
    __syncthreads();
#pragma unroll
    for (int ks = 0; ks < 2; ++ks) {
      short8 av[4], bv[4];
#pragma unroll
      for (int mi = 0; mi < 4; ++mi)
        av[mi] = *(const short8*)(lA + (wr * 64 + mi * 16 + (lane & 15)) * 64 + ks * 32 + ((lane >> 4) << 3));
#pragma unroll
      for (int ni = 0; ni < 4; ++ni)
        bv[ni] = *(const short8*)(lB + (wc * 64 + ni * 16 + (lane & 15)) * 64 + ks * 32 + ((lane >> 4) << 3));
#pragma unroll
      for (int mi = 0; mi < 4; ++mi)
#pragma unroll
        for (int ni = 0; ni < 4; ++ni)
          acc[mi][ni] = __builtin_amdgcn_mfma_f32_16x16x32_bf16(av[mi], bv[ni], acc[mi][ni], 0, 0, 0);
    }
    __syncthreads();
  }

  const int rg = lane >> 4;
  const int ci = lane & 15;
#pragma unroll
  for (int mi = 0; mi < 4; ++mi) {
#pragma unroll
    for (int ni = 0; ni < 4; ++ni) {
      const int col = n0 + wc * 64 + ni * 16 + ci;
      const float bvl = bias[col];
#pragma unroll
      for (int r = 0; r < 4; ++r) {
        const int row = m0 + wr * 64 + mi * 16 + rg * 4 + r;
        const float v = acc[mi][ni][r] + bvl;
        float o;
        if (gate == 0 || gate == 1)  o = 1.f / (1.f + __expf(-v));
        else if (gate == 2)          o = 1.f - 2.f / (1.f + __expf(2.f * v));
        else if (gate == 3)          o = 0.5f / (1.f + __expf(-v));
        else                         o = v;
        dst[(size_t)row * 512 + col] = o;
      }
    }
  }
}

__global__ __launch_bounds__(256) void cell_update(
    const float* __restrict__ cell, const float* ig, const float* og, const float* cg,
    const float* mem, float* upd, float* __restrict__ hid)
{
  const size_t idx = ((size_t)blockIdx.x * 256 + threadIdx.x) * 4;
  const f32x4 dv = *(const f32x4*)(mem + idx);
  const f32x4 iv = *(const f32x4*)(ig + idx);
  const f32x4 ov = *(const f32x4*)(og + idx);
  const f32x4 gv = *(const f32x4*)(cg + idx);
  asm volatile("" ::: "memory");
  float p[4], acc[4];
#pragma unroll
  for (int j = 0; j < 4; ++j) { p[j] = 1.f; acc[j] = 0.f; }
#pragma unroll
  for (int i = 0; i < 32; ++i) {
    const int k = 31 - i;
    const f32x4 c = *(const f32x4*)(cell + (size_t)k * BH + idx);
    const float inv = 1.f / (float)(i + 1);
#pragma unroll
    for (int j = 0; j < 4; ++j) {
      p[j] *= ((float)i - dv[j]) * inv;
      acc[j] += c[j] * p[j];
    }
    if (k >= 1) *(f32x4*)(upd + (size_t)(k - 1) * BH + idx) = c;
  }
  f32x4 cno, ho;
#pragma unroll
  for (int j = 0; j < 4; ++j) {
    const float cn = -acc[j] + gv[j] * iv[j];
    cno[j] = cn;
    const float th = 1.f - 2.f / (1.f + __expf(2.f * cn));
    ho[j] = ov[j] * th;
  }
  *(f32x4*)(upd + (size_t)31 * BH + idx) = cno;
  *(f32x4*)(hid + idx) = ho;
}

// ============================ launch ============================

extern "C" void kernel_launch(void* const* d_in, const int* in_sizes, int n_in,
                              void* d_out, int out_size, void* d_ws, size_t ws_size,
                              hipStream_t stream) {
  const float* sample = (const float*)d_in[0];
  const float* hidden = (const float*)d_in[1];
  const float* cell   = (const float*)d_in[2];
  const float* memp   = (const float*)d_in[3];

  float* out0 = (float*)d_out;                 // [B,O]   output
  float* hid  = out0 + (size_t)BH;             // [B,H]   hidden_new
  float* upd  = hid + (size_t)BH;              // [K,B,H] updated_cell_states
  float* memo = upd + (size_t)NK * BH;         // [B,H]   mem_new

  if (ws_size >= FAST_NEED_BYTES) {
    short* ws = (short*)d_ws;
    hipLaunchKernelGGL(prep, dim3(8704), dim3(256), 0, stream,
                       sample, hidden, memp,
                       (const float*)d_in[4], (const float*)d_in[6],
                       (const float*)d_in[10], (const float*)d_in[8],
                       (const float*)d_in[12], ws);
    FastArgs a;
    a.xh = ws + WS_XH; a.mempb = ws + WS_MEMPB; a.hidb = ws + WS_HIDB;
    a.W[0] = ws + WS_WI; a.W[1] = ws + WS_WO; a.W[2] = ws + WS_WC;
    a.W[3] = ws + WS_WM; a.W[4] = ws + WS_WOUT;
    a.bia[0] = (const float*)d_in[5];  a.bia[1] = (const float*)d_in[7];
    a.bia[2] = (const float*)d_in[11]; a.bia[3] = (const float*)d_in[9];
    a.bia[4] = (const float*)d_in[13];
    a.gdst[0] = ws + WS_IGB; a.gdst[1] = ws + WS_OGB; a.gdst[2] = ws + WS_CGB;
    a.memo = memo; a.out0 = out0;

    hipLaunchKernelGGL(gemm_fast, dim3(64, 16), dim3(256), 0, stream, a, 0);
    hipLaunchKernelGGL(cell_update_b, dim3(2048), dim3(256), 0, stream,
                       cell, (const short*)a.gdst[0], (const short*)a.gdst[1],
                       (const short*)a.gdst[2], (const float*)memo, upd, hid,
                       ws + WS_HIDB);
    hipLaunchKernelGGL(gemm_fast, dim3(64, 4), dim3(256), 0, stream, a, 1);
    return;
  }

  // fallback: round-3 path (passed)
  float* ig;
  float* og;
  float* cg;
  if (ws_size >= (size_t)3 * BH * sizeof(float)) {
    ig = (float*)d_ws; og = ig + (size_t)BH; cg = og + (size_t)BH;
  } else {
    ig = upd; og = upd + (size_t)BH; cg = upd + 2 * (size_t)BH;
  }
  GemmArgs g;
  g.sample = sample; g.hidden = hidden; g.memp = memp; g.hid_in = hid;
  g.W[0] = (const float*)d_in[4];  g.bia[0] = (const float*)d_in[5];
  g.W[1] = (const float*)d_in[6];  g.bia[1] = (const float*)d_in[7];
  g.W[3] = (const float*)d_in[8];  g.bia[3] = (const float*)d_in[9];
  g.W[2] = (const float*)d_in[10]; g.bia[2] = (const float*)d_in[11];
  g.W[4] = (const float*)d_in[12]; g.bia[4] = (const float*)d_in[13];
  g.dst[0] = ig; g.dst[1] = og; g.dst[2] = cg; g.dst[3] = memo; g.dst[4] = out0;

  hipLaunchKernelGGL(gemm_all, dim3(32, 16), dim3(256), 0, stream, g, 0);
  hipLaunchKernelGGL(cell_update, dim3(2048), dim3(256), 0, stream,
                     cell, (const float*)ig, (const float*)og, (const float*)cg,
                     (const float*)memo, upd, hid);
  hipLaunchKernelGGL(gemm_all, dim3(32, 4), dim3(256), 0, stream, g, 1);
}

// Round 11
// 186.819 us; speedup vs baseline: 1.1361x; 1.0025x over previous
//
#include <hip/hip_runtime.h>

typedef __attribute__((ext_vector_type(8))) short short8;
typedef __attribute__((ext_vector_type(4))) short sh4;
typedef __attribute__((ext_vector_type(4))) float f32x4;

#define BH 2097152   // B*H = 4096*512
#define NK 32

// f32 -> bf16 round-to-nearest-even
static __device__ __forceinline__ short f2bf(float f) {
  union { float f; unsigned int u; } c; c.f = f;
  unsigned int u = c.u + 0x7FFFu + ((c.u >> 16) & 1u);
  return (short)(u >> 16);
}
static __device__ __forceinline__ float bf2f(short s) {
  union { unsigned int u; float f; } c;
  c.u = ((unsigned int)(unsigned short)s) << 16;
  return c.f;
}
static __device__ __forceinline__ f32x4 ntload(const float* p) {
  return __builtin_nontemporal_load((const f32x4*)p);
}
static __device__ __forceinline__ void ntstore(float* p, f32x4 v) {
  __builtin_nontemporal_store(v, (f32x4*)p);
}

// ---------------- ws layout (shorts) ----------------
#define WS_XH     0          // [4096][1024] bf16 concat(sample,hidden)
#define WS_MEMPB  4194304    // [4096][512]
#define WS_WI     6291456    // [512][1024]
#define WS_WO     6815744
#define WS_WC     7340032
#define WS_WM     7864320    // [512][1536]
#define WS_WOUT   8650752    // [512][512]
#define WS_HIDB   8912896    // [4096][512] bf16 hidden_new
#define WS_IGB    11010048   // [4096][512] bf16 gates
#define WS_OGB    13107200
#define WS_CGB    15204352
#define WS_END    17301504
#define FAST_NEED_BYTES ((size_t)WS_END * 2)

// ============================ FAST PATH ============================

__global__ __launch_bounds__(256) void prep(
    const float* __restrict__ sample, const float* __restrict__ hidden,
    const float* __restrict__ memp,
    const float* __restrict__ wi, const float* __restrict__ wo,
    const float* __restrict__ wc, const float* __restrict__ wm,
    const float* __restrict__ wout, short* __restrict__ ws) {
  const size_t v = ((size_t)blockIdx.x * 256 + threadIdx.x) * 4;
  const float* src;
  short* dst;
  if (v < 2097152) {                     // sample -> xh[:, :512]
    const size_t r = v >> 9, c = v & 511;
    src = sample + v; dst = ws + WS_XH + r * 1024 + c;
  } else if (v < 4194304) {              // hidden -> xh[:, 512:]
    const size_t u = v - 2097152, r = u >> 9, c = u & 511;
    src = hidden + u; dst = ws + WS_XH + r * 1024 + 512 + c;
  } else if (v < 6291456) {              // memp
    const size_t u = v - 4194304; src = memp + u; dst = ws + WS_MEMPB + u;
  } else if (v < 6815744) {
    const size_t u = v - 6291456; src = wi + u; dst = ws + WS_WI + u;
  } else if (v < 7340032) {
    const size_t u = v - 6815744; src = wo + u; dst = ws + WS_WO + u;
  } else if (v < 7864320) {
    const size_t u = v - 7340032; src = wc + u; dst = ws + WS_WC + u;
  } else if (v < 8650752) {
    const size_t u = v - 7864320; src = wm + u; dst = ws + WS_WM + u;
  } else {                               // wout, ends at 8912896
    const size_t u = v - 8650752; src = wout + u; dst = ws + WS_WOUT + u;
  }
  const f32x4 x = *(const f32x4*)src;
  sh4 s;
#pragma unroll
  for (int j = 0; j < 4; ++j) s[j] = f2bf(x[j]);
  *(sh4*)dst = s;
}

struct FastArgs {
  const short *xh, *mempb, *hidb;
  const short *W[5];
  const float *bia[5];
  short *gdst[3];     // igb, ogb, cgb (bf16)
  float *memo, *out0; // f32 outputs
};

// bf16 GEMM, 64x64 tile, BK=64. Grid 2048 blocks for gates -> ~6 blocks/CU
// (VGPR-bound at ~80; LDS 16KB not binding). Co-residency is the proven
// lever for this 2-phase structure (r10: 2->4 blocks/CU was -12us).
// mode0: gate via gmap {m,i,o,c} of y>>3; nsub=y&7.  mode1: gate4 out GEMM.
__global__ __launch_bounds__(256) void gemm_fast(FastArgs a, int mode) {
  __shared__ short lA[64 * 64];
  __shared__ short lB[64 * 64];
  const int t = threadIdx.x;
  const int lane = t & 63;
  const int wv = t >> 6;
  const int mt = blockIdx.x;
  int gate, nsub;
  if (mode == 0) {
    const int gmap[4] = {3, 0, 1, 2};   // m first (longest K)
    gate = gmap[blockIdx.y >> 3]; nsub = blockIdx.y & 7;
  } else { gate = 4; nsub = blockIdx.y; }
  const short* W = a.W[gate];
  const int Klen = (gate == 3) ? 1536 : (gate == 4 ? 512 : 1024);
  const int m0 = mt * 64;
  const int n0 = nsub * 64;

  f32x4 acc[2][2];
  const f32x4 z = {0.f, 0.f, 0.f, 0.f};
#pragma unroll
  for (int i = 0; i < 2; ++i)
#pragma unroll
    for (int j = 0; j < 2; ++j) acc[i][j] = z;

  const int wr = wv >> 1, wc2 = wv & 1;   // wave sub-tile: 32 x 32
  const int Ktiles = Klen >> 6;
  for (int kt = 0; kt < Ktiles; ++kt) {
    const int kb = kt << 6;
    // stage A tile [64 rows][64 k]: 2 passes x 256 threads x 16B (linear dest)
#pragma unroll
    for (int it = 0; it < 2; ++it) {
      const int chunk = it * 256 + t;
      const int row = chunk >> 3;          // 0..63
      const int kk = (chunk & 7) << 3;     // 0..56
      const int gk = kb + kk;
      const short* src;
      if (gate == 4)                    src = a.hidb  + (size_t)(m0 + row) * 512 + gk;
      else if (gate != 3 || gk < 1024)  src = a.xh    + (size_t)(m0 + row) * 1024 + gk;
      else                              src = a.mempb + (size_t)(m0 + row) * 512 + (gk - 1024);
      __builtin_amdgcn_global_load_lds(
          (const __attribute__((address_space(1))) void*)src,
          (__attribute__((address_space(3))) void*)(lA + (size_t)(it * 256 + wv * 64) * 8),
          16, 0, 0);
    }
    // stage W tile [64 n][64 k]: 2 passes
#pragma unroll
    for (int it = 0; it < 2; ++it) {
      const int chunk = it * 256 + t;
      const int row = chunk >> 3;
      const int kk = (chunk & 7) << 3;
      const short* src = W + (size_t)(n0 + row) * Klen + kb + kk;
      __builtin_amdgcn_global_load_lds(
          (const __attribute__((address_space(1))) void*)src,
          (__attribute__((address_space(3))) void*)(lB + (size_t)(it * 256 + wv * 64) * 8),
          16, 0, 0);
    }
    __syncthreads();
#pragma unroll
    for (int ks = 0; ks < 2; ++ks) {
      short8 av[2], bv[2];
#pragma unroll
      for (int mi = 0; mi < 2; ++mi)
        av[mi] = *(const short8*)(lA + (wr * 32 + mi * 16 + (lane & 15)) * 64 + ks * 32 + ((lane >> 4) << 3));
#pragma unroll
      for (int ni = 0; ni < 2; ++ni)
        bv[ni] = *(const short8*)(lB + (wc2 * 32 + ni * 16 + (lane & 15)) * 64 + ks * 32 + ((lane >> 4) << 3));
#pragma unroll
      for (int mi = 0; mi < 2; ++mi)
#pragma unroll
        for (int ni = 0; ni < 2; ++ni)
          acc[mi][ni] = __builtin_amdgcn_mfma_f32_16x16x32_bf16(av[mi], bv[ni], acc[mi][ni], 0, 0, 0);
    }
    __syncthreads();
  }

  // epilogue: C/D layout col = lane&15 (n), row = 4*(lane>>4)+r (m)
  const float* bias = a.bia[gate];
  const int rg = lane >> 4;
  const int ci = lane & 15;
#pragma unroll
  for (int mi = 0; mi < 2; ++mi) {
#pragma unroll
    for (int ni = 0; ni < 2; ++ni) {
      const int col = n0 + wc2 * 32 + ni * 16 + ci;
      const float bvl = bias[col];
#pragma unroll
      for (int r = 0; r < 4; ++r) {
        const int row = m0 + wr * 32 + mi * 16 + rg * 4 + r;
        const float v = acc[mi][ni][r] + bvl;
        const size_t o = (size_t)row * 512 + col;
        if (gate == 0)      a.gdst[0][o] = f2bf(1.f / (1.f + __expf(-v)));
        else if (gate == 1) a.gdst[1][o] = f2bf(1.f / (1.f + __expf(-v)));
        else if (gate == 2) a.gdst[2][o] = f2bf(1.f - 2.f / (1.f + __expf(2.f * v)));
        else if (gate == 3) a.memo[o] = 0.5f / (1.f + __expf(-v));
        else                a.out0[o] = v;
      }
    }
  }
}

// Fused cumprod filter + cell shift + cell_new + hidden_new (+ bf16 hidden copy).
// Nontemporal on the single-use streams; (256,8) -> 32 waves/CU.
__global__ __launch_bounds__(256, 8) void cell_update_b(
    const float* __restrict__ cell, const short* __restrict__ igb,
    const short* __restrict__ ogb, const short* __restrict__ cgb,
    const float* __restrict__ mem, float* __restrict__ upd,
    float* __restrict__ hid, short* __restrict__ hidb)
{
  const size_t idx = ((size_t)blockIdx.x * 256 + threadIdx.x) * 4;
  const f32x4 dv = *(const f32x4*)(mem + idx);
  const sh4 iv = *(const sh4*)(igb + idx);
  const sh4 ov = *(const sh4*)(ogb + idx);
  const sh4 gv = *(const sh4*)(cgb + idx);
  float p[4], acc[4];
#pragma unroll
  for (int j = 0; j < 4; ++j) { p[j] = 1.f; acc[j] = 0.f; }
#pragma unroll
  for (int i = 0; i < 32; ++i) {
    const int k = 31 - i;
    const f32x4 c = ntload(cell + (size_t)k * BH + idx);
    const float inv = 1.f / (float)(i + 1);
#pragma unroll
    for (int j = 0; j < 4; ++j) {
      p[j] *= ((float)i - dv[j]) * inv;    // cumprod factor (i - d)/(i+1)
      acc[j] += c[j] * p[j];
    }
    if (k >= 1) ntstore(upd + (size_t)(k - 1) * BH + idx, c);  // shift copy
  }
  f32x4 cno, ho; sh4 hb;
#pragma unroll
  for (int j = 0; j < 4; ++j) {
    const float cn = -acc[j] + bf2f(gv[j]) * bf2f(iv[j]);
    cno[j] = cn;
    const float th = 1.f - 2.f / (1.f + __expf(2.f * cn));  // tanh, overflow-safe
    const float h = bf2f(ov[j]) * th;
    ho[j] = h; hb[j] = f2bf(h);
  }
  ntstore(upd + (size_t)31 * BH + idx, cno);
  *(f32x4*)(hid + idx) = ho;
  *(sh4*)(hidb + idx) = hb;
}

// ============================ FALLBACK (round-3, passed) ============================

struct GemmArgs {
  const float *sample, *hidden, *memp, *hid_in;
  const float *W[5];
  const float *bia[5];
  float *dst[5];
};

__global__ __launch_bounds__(256) void gemm_all(GemmArgs g, int mode) {
  __shared__ short lA[128 * 64];
  __shared__ short lB[128 * 64];
  const int t = threadIdx.x;
  const int lane = t & 63;
  const int mt = blockIdx.x;
  int gate, nsub;
  if (mode == 0) { gate = blockIdx.y >> 2; nsub = blockIdx.y & 3; }
  else           { gate = 4;               nsub = blockIdx.y; }
  const float* W = g.W[gate];
  const float* bias = g.bia[gate];
  float* dst = g.dst[gate];
  const int Klen = (gate == 3) ? 1536 : (gate == 4 ? 512 : 1024);
  const int m0 = mt * 128;
  const int n0 = nsub * 128;

  f32x4 acc[4][4];
  const f32x4 z = {0.f, 0.f, 0.f, 0.f};
#pragma unroll
  for (int i = 0; i < 4; ++i)
#pragma unroll
    for (int j = 0; j < 4; ++j) acc[i][j] = z;

  const int wv = t >> 6;
  const int wr = wv >> 1, wc = wv & 1;
  const int Ktiles = Klen >> 6;
  for (int kt = 0; kt < Ktiles; ++kt) {
    const int kb = kt << 6;
#pragma unroll
    for (int it = 0; it < 4; ++it) {
      const int chunk = it * 256 + t;
      const int row = chunk >> 3;
      const int kk = (chunk & 7) << 3;
      const int gk = kb + kk;
      const float* src;
      if (mode == 1)      src = g.hid_in + (size_t)(m0 + row) * 512 + gk;
      else if (gk < 512)  src = g.sample + (size_t)(m0 + row) * 512 + gk;
      else if (gk < 1024) src = g.hidden + (size_t)(m0 + row) * 512 + (gk - 512);
      else                src = g.memp   + (size_t)(m0 + row) * 512 + (gk - 1024);
      const f32x4 v0 = *(const f32x4*)src;
      const f32x4 v1 = *(const f32x4*)(src + 4);
      short8 s;
#pragma unroll
      for (int j = 0; j < 4; ++j) { s[j] = f2bf(v0[j]); s[4 + j] = f2bf(v1[j]); }
      *(short8*)(lA + row * 64 + kk) = s;
    }
#pragma unroll
    for (int it = 0; it < 4; ++it) {
      const int chunk = it * 256 + t;
      const int row = chunk >> 3;
      const int kk = (chunk & 7) << 3;
      const float* src = W + (size_t)(n0 + row) * Klen + kb + kk;
      const f32x4 v0 = *(const f32x4*)src;
      const f32x4 v1 = *(const f32x4*)(src + 4);
      short8 s;
#pragma unroll
      for (int j = 0; j < 4; ++j) { s[j] = f2bf(v0[j]); s[4 + j] = f2bf(v1[j]); }
      *(short8*)(lB + row * 64 + kk) = s;
    }
    __syncthreads();
#pragma unroll
    for (int ks = 0; ks < 2; ++ks) {
      short8 av[4], bv[4];
#pragma unroll
      for (int mi = 0; mi < 4; ++mi)
        av[mi] = *(const short8*)(lA + (wr * 64 + mi * 16 + (lane & 15)) * 64 + ks * 32 + ((lane >> 4) << 3));
#pragma unroll
      for (int ni = 0; ni < 4; ++ni)
        bv[ni] = *(const short8*)(lB + (wc * 64 + ni * 16 + (lane & 15)) * 64 + ks * 32 + ((lane >> 4) << 3));
#pragma unroll
      for (int mi = 0; mi < 4; ++mi)
#pragma unroll
        for (int ni = 0; ni < 4; ++ni)
          acc[mi][ni] = __builtin_amdgcn_mfma_f32_16x16x32_bf16(av[mi], bv[ni], acc[mi][ni], 0, 0, 0);
    }
    __syncthreads();
  }

  const int rg = lane >> 4;
  const int ci = lane & 15;
#pragma unroll
  for (int mi = 0; mi < 4; ++mi) {
#pragma unroll
    for (int ni = 0; ni < 4; ++ni) {
      const int col = n0 + wc * 64 + ni * 16 + ci;
      const float bvl = bias[col];
#pragma unroll
      for (int r = 0; r < 4; ++r) {
        const int row = m0 + wr * 64 + mi * 16 + rg * 4 + r;
        const float v = acc[mi][ni][r] + bvl;
        float o;
        if (gate == 0 || gate == 1)  o = 1.f / (1.f + __expf(-v));
        else if (gate == 2)          o = 1.f - 2.f / (1.f + __expf(2.f * v));
        else if (gate == 3)          o = 0.5f / (1.f + __expf(-v));
        else                         o = v;
        dst[(size_t)row * 512 + col] = o;
      }
    }
  }
}

__global__ __launch_bounds__(256) void cell_update(
    const float* __restrict__ cell, const float* ig, const float* og, const float* cg,
    const float* mem, float* upd, float* __restrict__ hid)
{
  const size_t idx = ((size_t)blockIdx.x * 256 + threadIdx.x) * 4;
  const f32x4 dv = *(const f32x4*)(mem + idx);
  const f32x4 iv = *(const f32x4*)(ig + idx);
  const f32x4 ov = *(const f32x4*)(og + idx);
  const f32x4 gv = *(const f32x4*)(cg + idx);
  asm volatile("" ::: "memory");
  float p[4], acc[4];
#pragma unroll
  for (int j = 0; j < 4; ++j) { p[j] = 1.f; acc[j] = 0.f; }
#pragma unroll
  for (int i = 0; i < 32; ++i) {
    const int k = 31 - i;
    const f32x4 c = *(const f32x4*)(cell + (size_t)k * BH + idx);
    const float inv = 1.f / (float)(i + 1);
#pragma unroll
    for (int j = 0; j < 4; ++j) {
      p[j] *= ((float)i - dv[j]) * inv;
      acc[j] += c[j] * p[j];
    }
    if (k >= 1) *(f32x4*)(upd + (size_t)(k - 1) * BH + idx) = c;
  }
  f32x4 cno, ho;
#pragma unroll
  for (int j = 0; j < 4; ++j) {
    const float cn = -acc[j] + gv[j] * iv[j];
    cno[j] = cn;
    const float th = 1.f - 2.f / (1.f + __expf(2.f * cn));
    ho[j] = ov[j] * th;
  }
  *(f32x4*)(upd + (size_t)31 * BH + idx) = cno;
  *(f32x4*)(hid + idx) = ho;
}

// ============================ launch ============================

extern "C" void kernel_launch(void* const* d_in, const int* in_sizes, int n_in,
                              void* d_out, int out_size, void* d_ws, size_t ws_size,
                              hipStream_t stream) {
  const float* sample = (const float*)d_in[0];
  const float* hidden = (const float*)d_in[1];
  const float* cell   = (const float*)d_in[2];
  const float* memp   = (const float*)d_in[3];

  float* out0 = (float*)d_out;                 // [B,O]   output
  float* hid  = out0 + (size_t)BH;             // [B,H]   hidden_new
  float* upd  = hid + (size_t)BH;              // [K,B,H] updated_cell_states
  float* memo = upd + (size_t)NK * BH;         // [B,H]   mem_new

  if (ws_size >= FAST_NEED_BYTES) {
    short* ws = (short*)d_ws;
    hipLaunchKernelGGL(prep, dim3(8704), dim3(256), 0, stream,
                       sample, hidden, memp,
                       (const float*)d_in[4], (const float*)d_in[6],
                       (const float*)d_in[10], (const float*)d_in[8],
                       (const float*)d_in[12], ws);
    FastArgs a;
    a.xh = ws + WS_XH; a.mempb = ws + WS_MEMPB; a.hidb = ws + WS_HIDB;
    a.W[0] = ws + WS_WI; a.W[1] = ws + WS_WO; a.W[2] = ws + WS_WC;
    a.W[3] = ws + WS_WM; a.W[4] = ws + WS_WOUT;
    a.bia[0] = (const float*)d_in[5];  a.bia[1] = (const float*)d_in[7];
    a.bia[2] = (const float*)d_in[11]; a.bia[3] = (const float*)d_in[9];
    a.bia[4] = (const float*)d_in[13];
    a.gdst[0] = ws + WS_IGB; a.gdst[1] = ws + WS_OGB; a.gdst[2] = ws + WS_CGB;
    a.memo = memo; a.out0 = out0;

    hipLaunchKernelGGL(gemm_fast, dim3(64, 32), dim3(256), 0, stream, a, 0);
    hipLaunchKernelGGL(cell_update_b, dim3(2048), dim3(256), 0, stream,
                       cell, (const short*)a.gdst[0], (const short*)a.gdst[1],
                       (const short*)a.gdst[2], (const float*)memo, upd, hid,
                       ws + WS_HIDB);
    hipLaunchKernelGGL(gemm_fast, dim3(64, 8), dim3(256), 0, stream, a, 1);
    return;
  }

  // fallback: round-3 path (passed)
  float* ig;
  float* og;
  float* cg;
  if (ws_size >= (size_t)3 * BH * sizeof(float)) {
    ig = (float*)d_ws; og = ig + (size_t)BH; cg = og + (size_t)BH;
  } else {
    ig = upd; og = upd + (size_t)BH; cg = upd + 2 * (size_t)BH;
  }
  GemmArgs g;
  g.sample = sample; g.hidden = hidden; g.memp = memp; g.hid_in = hid;
  g.W[0] = (const float*)d_in[4];  g.bia[0] = (const float*)d_in[5];
  g.W[1] = (const float*)d_in[6];  g.bia[1] = (const float*)d_in[7];
  g.W[3] = (const float*)d_in[8];  g.bia[3] = (const float*)d_in[9];
  g.W[2] = (const float*)d_in[10]; g.bia[2] = (const float*)d_in[11];
  g.W[4] = (const float*)d_in[12]; g.bia[4] = (const float*)d_in[13];
  g.dst[0] = ig; g.dst[1] = og; g.dst[2] = cg; g.dst[3] = memo; g.dst[4] = out0;

  hipLaunchKernelGGL(gemm_all, dim3(32, 16), dim3(256), 0, stream, g, 0);
  hipLaunchKernelGGL(cell_update, dim3(2048), dim3(256), 0, stream,
                     cell, (const float*)ig, (const float*)og, (const float*)cg,
                     (const float*)memo, upd, hid);
  hipLaunchKernelGGL(gemm_all, dim3(32, 4), dim3(256), 0, stream, g, 1);
}

// Round 12
// 185.440 us; speedup vs baseline: 1.1445x; 1.0074x over previous
//
#include <hip/hip_runtime.h>

typedef __attribute__((ext_vector_type(8))) short short8;
typedef __attribute__((ext_vector_type(4))) short sh4;
typedef __attribute__((ext_vector_type(4))) float f32x4;

#define BH 2097152   // B*H = 4096*512
#define NK 32

// f32 -> bf16 round-to-nearest-even
static __device__ __forceinline__ short f2bf(float f) {
  union { float f; unsigned int u; } c; c.f = f;
  unsigned int u = c.u + 0x7FFFu + ((c.u >> 16) & 1u);
  return (short)(u >> 16);
}
static __device__ __forceinline__ float bf2f(short s) {
  union { unsigned int u; float f; } c;
  c.u = ((unsigned int)(unsigned short)s) << 16;
  return c.f;
}
static __device__ __forceinline__ f32x4 ntload(const float* p) {
  return __builtin_nontemporal_load((const f32x4*)p);
}
static __device__ __forceinline__ void ntstore(float* p, f32x4 v) {
  __builtin_nontemporal_store(v, (f32x4*)p);
}

// ---------------- ws layout (shorts) ----------------
#define WS_XH     0          // [4096][1024] bf16 concat(sample,hidden)
#define WS_MEMPB  4194304    // [4096][512]
#define WS_WI     6291456    // [512][1024]
#define WS_WO     6815744
#define WS_WC     7340032
#define WS_WM     7864320    // [512][1536]
#define WS_WOUT   8650752    // [512][512]
#define WS_HIDB   8912896    // [4096][512] bf16 hidden_new
#define WS_IGB    11010048   // [4096][512] bf16 gates
#define WS_OGB    13107200
#define WS_CGB    15204352
#define WS_END    17301504
#define FAST_NEED_BYTES ((size_t)WS_END * 2)

// ============================ FAST PATH ============================

__global__ __launch_bounds__(256) void prep(
    const float* __restrict__ sample, const float* __restrict__ hidden,
    const float* __restrict__ memp,
    const float* __restrict__ wi, const float* __restrict__ wo,
    const float* __restrict__ wc, const float* __restrict__ wm,
    const float* __restrict__ wout, short* __restrict__ ws) {
  const size_t v = ((size_t)blockIdx.x * 256 + threadIdx.x) * 4;
  const float* src;
  short* dst;
  if (v < 2097152) {                     // sample -> xh[:, :512]
    const size_t r = v >> 9, c = v & 511;
    src = sample + v; dst = ws + WS_XH + r * 1024 + c;
  } else if (v < 4194304) {              // hidden -> xh[:, 512:]
    const size_t u = v - 2097152, r = u >> 9, c = u & 511;
    src = hidden + u; dst = ws + WS_XH + r * 1024 + 512 + c;
  } else if (v < 6291456) {              // memp
    const size_t u = v - 4194304; src = memp + u; dst = ws + WS_MEMPB + u;
  } else if (v < 6815744) {
    const size_t u = v - 6291456; src = wi + u; dst = ws + WS_WI + u;
  } else if (v < 7340032) {
    const size_t u = v - 6815744; src = wo + u; dst = ws + WS_WO + u;
  } else if (v < 7864320) {
    const size_t u = v - 7340032; src = wc + u; dst = ws + WS_WC + u;
  } else if (v < 8650752) {
    const size_t u = v - 7864320; src = wm + u; dst = ws + WS_WM + u;
  } else {                               // wout, ends at 8912896
    const size_t u = v - 8650752; src = wout + u; dst = ws + WS_WOUT + u;
  }
  const f32x4 x = *(const f32x4*)src;
  sh4 s;
#pragma unroll
  for (int j = 0; j < 4; ++j) s[j] = f2bf(x[j]);
  *(sh4*)dst = s;
}

struct FastArgs {
  const short *xh, *mempb, *hidb;
  const short *W[5];
  const float *bia[5];
  short *gdst[3];     // igb, ogb, cgb (bf16)
  float *memo, *out0; // f32 outputs
};

// bf16 GEMM, 64x64 tile, BK=64, DOUBLE-BUFFERED LDS (T3 minimal 2-phase):
// issue next-tile global_load_lds BEFORE computing current tile; ONE barrier
// per K-step (its implicit vmcnt(0) drains the prefetch after compute).
// LDS 32KB -> 5 blocks/CU. Grid 2048 gate blocks.
// mode0: gate via gmap {m,i,o,c} of y>>3; nsub=y&7.  mode1: gate4 out GEMM.
__global__ __launch_bounds__(256) void gemm_fast(FastArgs a, int mode) {
  __shared__ short lA[2][64 * 64];
  __shared__ short lB[2][64 * 64];
  const int t = threadIdx.x;
  const int lane = t & 63;
  const int wv = t >> 6;
  const int mt = blockIdx.x;
  int gate, nsub;
  if (mode == 0) {
    const int gmap[4] = {3, 0, 1, 2};   // m first (longest K)
    gate = gmap[blockIdx.y >> 3]; nsub = blockIdx.y & 7;
  } else { gate = 4; nsub = blockIdx.y; }
  const short* W = a.W[gate];
  const int Klen = (gate == 3) ? 1536 : (gate == 4 ? 512 : 1024);
  const int m0 = mt * 64;
  const int n0 = nsub * 64;

  f32x4 acc[2][2];
  const f32x4 z = {0.f, 0.f, 0.f, 0.f};
#pragma unroll
  for (int i = 0; i < 2; ++i)
#pragma unroll
    for (int j = 0; j < 2; ++j) acc[i][j] = z;

  const int wr = wv >> 1, wc2 = wv & 1;   // wave sub-tile: 32 x 32

  // stage one 64x64 A-tile + W-tile into buffer `buf` for K-tile kt
  auto stage = [&](int buf, int kt) {
    const int kb = kt << 6;
#pragma unroll
    for (int it = 0; it < 2; ++it) {
      const int chunk = it * 256 + t;
      const int row = chunk >> 3;          // 0..63
      const int kk = (chunk & 7) << 3;     // 0..56
      const int gk = kb + kk;
      const short* src;
      if (gate == 4)                    src = a.hidb  + (size_t)(m0 + row) * 512 + gk;
      else if (gate != 3 || gk < 1024)  src = a.xh    + (size_t)(m0 + row) * 1024 + gk;
      else                              src = a.mempb + (size_t)(m0 + row) * 512 + (gk - 1024);
      __builtin_amdgcn_global_load_lds(
          (const __attribute__((address_space(1))) void*)src,
          (__attribute__((address_space(3))) void*)(&lA[buf][0] + (size_t)(it * 256 + wv * 64) * 8),
          16, 0, 0);
    }
#pragma unroll
    for (int it = 0; it < 2; ++it) {
      const int chunk = it * 256 + t;
      const int row = chunk >> 3;
      const int kk = (chunk & 7) << 3;
      const short* src = W + (size_t)(n0 + row) * Klen + kb + kk;
      __builtin_amdgcn_global_load_lds(
          (const __attribute__((address_space(1))) void*)src,
          (__attribute__((address_space(3))) void*)(&lB[buf][0] + (size_t)(it * 256 + wv * 64) * 8),
          16, 0, 0);
    }
  };

  const int Ktiles = Klen >> 6;
  stage(0, 0);
  __syncthreads();          // drains vmcnt(0): buf0 ready
  int cur = 0;
  for (int kt = 0; kt < Ktiles; ++kt) {
    if (kt + 1 < Ktiles) stage(cur ^ 1, kt + 1);   // prefetch overlaps compute
#pragma unroll
    for (int ks = 0; ks < 2; ++ks) {
      short8 av[2], bv[2];
#pragma unroll
      for (int mi = 0; mi < 2; ++mi)
        av[mi] = *(const short8*)(&lA[cur][0] + (wr * 32 + mi * 16 + (lane & 15)) * 64 + ks * 32 + ((lane >> 4) << 3));
#pragma unroll
      for (int ni = 0; ni < 2; ++ni)
        bv[ni] = *(const short8*)(&lB[cur][0] + (wc2 * 32 + ni * 16 + (lane & 15)) * 64 + ks * 32 + ((lane >> 4) << 3));
#pragma unroll
      for (int mi = 0; mi < 2; ++mi)
#pragma unroll
        for (int ni = 0; ni < 2; ++ni)
          acc[mi][ni] = __builtin_amdgcn_mfma_f32_16x16x32_bf16(av[mi], bv[ni], acc[mi][ni], 0, 0, 0);
    }
    __syncthreads();        // prefetch landed + all reads of buf[cur] done
    cur ^= 1;
  }

  // epilogue: C/D layout col = lane&15 (n), row = 4*(lane>>4)+r (m)
  const float* bias = a.bia[gate];
  const int rg = lane >> 4;
  const int ci = lane & 15;
#pragma unroll
  for (int mi = 0; mi < 2; ++mi) {
#pragma unroll
    for (int ni = 0; ni < 2; ++ni) {
      const int col = n0 + wc2 * 32 + ni * 16 + ci;
      const float bvl = bias[col];
#pragma unroll
      for (int r = 0; r < 4; ++r) {
        const int row = m0 + wr * 32 + mi * 16 + rg * 4 + r;
        const float v = acc[mi][ni][r] + bvl;
        const size_t o = (size_t)row * 512 + col;
        if (gate == 0)      a.gdst[0][o] = f2bf(1.f / (1.f + __expf(-v)));
        else if (gate == 1) a.gdst[1][o] = f2bf(1.f / (1.f + __expf(-v)));
        else if (gate == 2) a.gdst[2][o] = f2bf(1.f - 2.f / (1.f + __expf(2.f * v)));
        else if (gate == 3) a.memo[o] = 0.5f / (1.f + __expf(-v));
        else                a.out0[o] = v;
      }
    }
  }
}

// Fused cumprod filter + cell shift + cell_new + hidden_new (+ bf16 hidden copy).
// Nontemporal on the single-use streams; (256,8) -> 32 waves/CU.
__global__ __launch_bounds__(256, 8) void cell_update_b(
    const float* __restrict__ cell, const short* __restrict__ igb,
    const short* __restrict__ ogb, const short* __restrict__ cgb,
    const float* __restrict__ mem, float* __restrict__ upd,
    float* __restrict__ hid, short* __restrict__ hidb)
{
  const size_t idx = ((size_t)blockIdx.x * 256 + threadIdx.x) * 4;
  const f32x4 dv = *(const f32x4*)(mem + idx);
  const sh4 iv = *(const sh4*)(igb + idx);
  const sh4 ov = *(const sh4*)(ogb + idx);
  const sh4 gv = *(const sh4*)(cgb + idx);
  float p[4], acc[4];
#pragma unroll
  for (int j = 0; j < 4; ++j) { p[j] = 1.f; acc[j] = 0.f; }
#pragma unroll
  for (int i = 0; i < 32; ++i) {
    const int k = 31 - i;
    const f32x4 c = ntload(cell + (size_t)k * BH + idx);
    const float inv = 1.f / (float)(i + 1);
#pragma unroll
    for (int j = 0; j < 4; ++j) {
      p[j] *= ((float)i - dv[j]) * inv;    // cumprod factor (i - d)/(i+1)
      acc[j] += c[j] * p[j];
    }
    if (k >= 1) ntstore(upd + (size_t)(k - 1) * BH + idx, c);  // shift copy
  }
  f32x4 cno, ho; sh4 hb;
#pragma unroll
  for (int j = 0; j < 4; ++j) {
    const float cn = -acc[j] + bf2f(gv[j]) * bf2f(iv[j]);
    cno[j] = cn;
    const float th = 1.f - 2.f / (1.f + __expf(2.f * cn));  // tanh, overflow-safe
    const float h = bf2f(ov[j]) * th;
    ho[j] = h; hb[j] = f2bf(h);
  }
  ntstore(upd + (size_t)31 * BH + idx, cno);
  *(f32x4*)(hid + idx) = ho;
  *(sh4*)(hidb + idx) = hb;
}

// ============================ FALLBACK (round-3, passed) ============================

struct GemmArgs {
  const float *sample, *hidden, *memp, *hid_in;
  const float *W[5];
  const float *bia[5];
  float *dst[5];
};

__global__ __launch_bounds__(256) void gemm_all(GemmArgs g, int mode) {
  __shared__ short lA[128 * 64];
  __shared__ short lB[128 * 64];
  const int t = threadIdx.x;
  const int lane = t & 63;
  const int mt = blockIdx.x;
  int gate, nsub;
  if (mode == 0) { gate = blockIdx.y >> 2; nsub = blockIdx.y & 3; }
  else           { gate = 4;               nsub = blockIdx.y; }
  const float* W = g.W[gate];
  const float* bias = g.bia[gate];
  float* dst = g.dst[gate];
  const int Klen = (gate == 3) ? 1536 : (gate == 4 ? 512 : 1024);
  const int m0 = mt * 128;
  const int n0 = nsub * 128;

  f32x4 acc[4][4];
  const f32x4 z = {0.f, 0.f, 0.f, 0.f};
#pragma unroll
  for (int i = 0; i < 4; ++i)
#pragma unroll
    for (int j = 0; j < 4; ++j) acc[i][j] = z;

  const int wv = t >> 6;
  const int wr = wv >> 1, wc = wv & 1;
  const int Ktiles = Klen >> 6;
  for (int kt = 0; kt < Ktiles; ++kt) {
    const int kb = kt << 6;
#pragma unroll
    for (int it = 0; it < 4; ++it) {
      const int chunk = it * 256 + t;
      const int row = chunk >> 3;
      const int kk = (chunk & 7) << 3;
      const int gk = kb + kk;
      const float* src;
      if (mode == 1)      src = g.hid_in + (size_t)(m0 + row) * 512 + gk;
      else if (gk < 512)  src = g.sample + (size_t)(m0 + row) * 512 + gk;
      else if (gk < 1024) src = g.hidden + (size_t)(m0 + row) * 512 + (gk - 512);
      else                src = g.memp   + (size_t)(m0 + row) * 512 + (gk - 1024);
      const f32x4 v0 = *(const f32x4*)src;
      const f32x4 v1 = *(const f32x4*)(src + 4);
      short8 s;
#pragma unroll
      for (int j = 0; j < 4; ++j) { s[j] = f2bf(v0[j]); s[4 + j] = f2bf(v1[j]); }
      *(short8*)(lA + row * 64 + kk) = s;
    }
#pragma unroll
    for (int it = 0; it < 4; ++it) {
      const int chunk = it * 256 + t;
      const int row = chunk >> 3;
      const int kk = (chunk & 7) << 3;
      const float* src = W + (size_t)(n0 + row) * Klen + kb + kk;
      const f32x4 v0 = *(const f32x4*)src;
      const f32x4 v1 = *(const f32x4*)(src + 4);
      short8 s;
#pragma unroll
      for (int j = 0; j < 4; ++j) { s[j] = f2bf(v0[j]); s[4 + j] = f2bf(v1[j]); }
      *(short8*)(lB + row * 64 + kk) = s;
    }
    __syncthreads();
#pragma unroll
    for (int ks = 0; ks < 2; ++ks) {
      short8 av[4], bv[4];
#pragma unroll
      for (int mi = 0; mi < 4; ++mi)
        av[mi] = *(const short8*)(lA + (wr * 64 + mi * 16 + (lane & 15)) * 64 + ks * 32 + ((lane >> 4) << 3));
#pragma unroll
      for (int ni = 0; ni < 4; ++ni)
        bv[ni] = *(const short8*)(lB + (wc * 64 + ni * 16 + (lane & 15)) * 64 + ks * 32 + ((lane >> 4) << 3));
#pragma unroll
      for (int mi = 0; mi < 4; ++mi)
#pragma unroll
        for (int ni = 0; ni < 4; ++ni)
          acc[mi][ni] = __builtin_amdgcn_mfma_f32_16x16x32_bf16(av[mi], bv[ni], acc[mi][ni], 0, 0, 0);
    }
    __syncthreads();
  }

  const int rg = lane >> 4;
  const int ci = lane & 15;
#pragma unroll
  for (int mi = 0; mi < 4; ++mi) {
#pragma unroll
    for (int ni = 0; ni < 4; ++ni) {
      const int col = n0 + wc * 64 + ni * 16 + ci;
      const float bvl = bias[col];
#pragma unroll
      for (int r = 0; r < 4; ++r) {
        const int row = m0 + wr * 64 + mi * 16 + rg * 4 + r;
        const float v = acc[mi][ni][r] + bvl;
        float o;
        if (gate == 0 || gate == 1)  o = 1.f / (1.f + __expf(-v));
        else if (gate == 2)          o = 1.f - 2.f / (1.f + __expf(2.f * v));
        else if (gate == 3)          o = 0.5f / (1.f + __expf(-v));
        else                         o = v;
        dst[(size_t)row * 512 + col] = o;
      }
    }
  }
}

__global__ __launch_bounds__(256) void cell_update(
    const float* __restrict__ cell, const float* ig, const float* og, const float* cg,
    const float* mem, float* upd, float* __restrict__ hid)
{
  const size_t idx = ((size_t)blockIdx.x * 256 + threadIdx.x) * 4;
  const f32x4 dv = *(const f32x4*)(mem + idx);
  const f32x4 iv = *(const f32x4*)(ig + idx);
  const f32x4 ov = *(const f32x4*)(og + idx);
  const f32x4 gv = *(const f32x4*)(cg + idx);
  asm volatile("" ::: "memory");
  float p[4], acc[4];
#pragma unroll
  for (int j = 0; j < 4; ++j) { p[j] = 1.f; acc[j] = 0.f; }
#pragma unroll
  for (int i = 0; i < 32; ++i) {
    const int k = 31 - i;
    const f32x4 c = *(const f32x4*)(cell + (size_t)k * BH + idx);
    const float inv = 1.f / (float)(i + 1);
#pragma unroll
    for (int j = 0; j < 4; ++j) {
      p[j] *= ((float)i - dv[j]) * inv;
      acc[j] += c[j] * p[j];
    }
    if (k >= 1) *(f32x4*)(upd + (size_t)(k - 1) * BH + idx) = c;
  }
  f32x4 cno, ho;
#pragma unroll
  for (int j = 0; j < 4; ++j) {
    const float cn = -acc[j] + gv[j] * iv[j];
    cno[j] = cn;
    const float th = 1.f - 2.f / (1.f + __expf(2.f * cn));
    ho[j] = ov[j] * th;
  }
  *(f32x4*)(upd + (size_t)31 * BH + idx) = cno;
  *(f32x4*)(hid + idx) = ho;
}

// ============================ launch ============================

extern "C" void kernel_launch(void* const* d_in, const int* in_sizes, int n_in,
                              void* d_out, int out_size, void* d_ws, size_t ws_size,
                              hipStream_t stream) {
  const float* sample = (const float*)d_in[0];
  const float* hidden = (const float*)d_in[1];
  const float* cell   = (const float*)d_in[2];
  const float* memp   = (const float*)d_in[3];

  float* out0 = (float*)d_out;                 // [B,O]   output
  float* hid  = out0 + (size_t)BH;             // [B,H]   hidden_new
  float* upd  = hid + (size_t)BH;              // [K,B,H] updated_cell_states
  float* memo = upd + (size_t)NK * BH;         // [B,H]   mem_new

  if (ws_size >= FAST_NEED_BYTES) {
    short* ws = (short*)d_ws;
    hipLaunchKernelGGL(prep, dim3(8704), dim3(256), 0, stream,
                       sample, hidden, memp,
                       (const float*)d_in[4], (const float*)d_in[6],
                       (const float*)d_in[10], (const float*)d_in[8],
                       (const float*)d_in[12], ws);
    FastArgs a;
    a.xh = ws + WS_XH; a.mempb = ws + WS_MEMPB; a.hidb = ws + WS_HIDB;
    a.W[0] = ws + WS_WI; a.W[1] = ws + WS_WO; a.W[2] = ws + WS_WC;
    a.W[3] = ws + WS_WM; a.W[4] = ws + WS_WOUT;
    a.bia[0] = (const float*)d_in[5];  a.bia[1] = (const float*)d_in[7];
    a.bia[2] = (const float*)d_in[11]; a.bia[3] = (const float*)d_in[9];
    a.bia[4] = (const float*)d_in[13];
    a.gdst[0] = ws + WS_IGB; a.gdst[1] = ws + WS_OGB; a.gdst[2] = ws + WS_CGB;
    a.memo = memo; a.out0 = out0;

    hipLaunchKernelGGL(gemm_fast, dim3(64, 32), dim3(256), 0, stream, a, 0);
    hipLaunchKernelGGL(cell_update_b, dim3(2048), dim3(256), 0, stream,
                       cell, (const short*)a.gdst[0], (const short*)a.gdst[1],
                       (const short*)a.gdst[2], (const float*)memo, upd, hid,
                       ws + WS_HIDB);
    hipLaunchKernelGGL(gemm_fast, dim3(64, 8), dim3(256), 0, stream, a, 1);
    return;
  }

  // fallback: round-3 path (passed)
  float* ig;
  float* og;
  float* cg;
  if (ws_size >= (size_t)3 * BH * sizeof(float)) {
    ig = (float*)d_ws; og = ig + (size_t)BH; cg = og + (size_t)BH;
  } else {
    ig = upd; og = upd + (size_t)BH; cg = upd + 2 * (size_t)BH;
  }
  GemmArgs g;
  g.sample = sample; g.hidden = hidden; g.memp = memp; g.hid_in = hid;
  g.W[0] = (const float*)d_in[4];  g.bia[0] = (const float*)d_in[5];
  g.W[1] = (const float*)d_in[6];  g.bia[1] = (const float*)d_in[7];
  g.W[3] = (const float*)d_in[8];  g.bia[3] = (const float*)d_in[9];
  g.W[2] = (const float*)d_in[10]; g.bia[2] = (const float*)d_in[11];
  g.W[4] = (const float*)d_in[12]; g.bia[4] = (const float*)d_in[13];
  g.dst[0] = ig; g.dst[1] = og; g.dst[2] = cg; g.dst[3] = memo; g.dst[4] = out0;

  hipLaunchKernelGGL(gemm_all, dim3(32, 16), dim3(256), 0, stream, g, 0);
  hipLaunchKernelGGL(cell_update, dim3(2048), dim3(256), 0, stream,
                     cell, (const float*)ig, (const float*)og, (const float*)cg,
                     (const float*)memo, upd, hid);
  hipLaunchKernelGGL(gemm_all, dim3(32, 4), dim3(256), 0, stream, g, 1);
}